// Round 4
// baseline (6490.405 us; speedup 1.0000x reference)
//
#include <hip/hip_runtime.h>
#include <math.h>

namespace {
constexpr int kB = 512;
constexpr int kT = 256;
constexpr int kD = 256;
constexpr int kS = 8;
constexpr int kStRow = 288;  // padded LDS row stride: +4 floats per 32 (bank swizzle)

__device__ __forceinline__ int physk(int k) { return k + ((k >> 5) << 2); }
}

// ---------------------------------------------------------------------------
// Kernel A: XW[b,t,:] = inputs[b,t,:] @ W, skipping t >= lengths[b].
// ---------------------------------------------------------------------------
__global__ __launch_bounds__(256, 2)
void xw_gemm_kernel(const float* __restrict__ X, const float* __restrict__ W,
                    const int* __restrict__ lengths, float* __restrict__ XW) {
  const int m0 = blockIdx.x * 32;
  const int b = m0 >> 8;
  const int t0 = m0 & 255;
  if (t0 >= lengths[b]) return;

  __shared__ float Xs[32][kD];
  const int tid = threadIdx.x;
  const int j  = tid & 63;
  const int rg = tid >> 6;

  const float4* Xg4 = (const float4*)(X + (size_t)m0 * kD);
  float4* Xs4 = (float4*)&Xs[0][0];
  for (int i = tid; i < 32 * kD / 4; i += 256) Xs4[i] = Xg4[i];
  __syncthreads();

  float4 acc[8];
#pragma unroll
  for (int i = 0; i < 8; ++i) acc[i] = make_float4(0.f, 0.f, 0.f, 0.f);

  const float4* W4 = (const float4*)W;
  const float4* Xrow = (const float4*)&Xs[rg * 8][0];

  for (int k4 = 0; k4 < kD / 4; ++k4) {
    float4 w0 = W4[(size_t)(4 * k4 + 0) * 64 + j];
    float4 w1 = W4[(size_t)(4 * k4 + 1) * 64 + j];
    float4 w2 = W4[(size_t)(4 * k4 + 2) * 64 + j];
    float4 w3 = W4[(size_t)(4 * k4 + 3) * 64 + j];
#pragma unroll
    for (int i = 0; i < 8; ++i) {
      float4 x = Xrow[i * 64 + k4];
      acc[i].x = fmaf(x.x, w0.x, fmaf(x.y, w1.x, fmaf(x.z, w2.x, fmaf(x.w, w3.x, acc[i].x))));
      acc[i].y = fmaf(x.x, w0.y, fmaf(x.y, w1.y, fmaf(x.z, w2.y, fmaf(x.w, w3.y, acc[i].y))));
      acc[i].z = fmaf(x.x, w0.z, fmaf(x.y, w1.z, fmaf(x.z, w2.z, fmaf(x.w, w3.z, acc[i].z))));
      acc[i].w = fmaf(x.x, w0.w, fmaf(x.y, w1.w, fmaf(x.z, w2.w, fmaf(x.w, w3.w, acc[i].w))));
    }
  }
  float4* XW4 = (float4*)XW;
#pragma unroll
  for (int i = 0; i < 8; ++i)
    XW4[(size_t)(m0 + rg * 8 + i) * 64 + j] = acc[i];
}

// ---------------------------------------------------------------------------
// Kernel B: GK[b,t,s] = inputs[b,t,:] . keys[s,:], t < lengths[b] only.
// ---------------------------------------------------------------------------
__global__ __launch_bounds__(256, 4)
void gk_kernel(const float* __restrict__ inputs, const float* __restrict__ keys,
               const int* __restrict__ lengths, float* __restrict__ GK) {
  const int b = blockIdx.x;
  const int tid = threadIdx.x;
  const int lane = tid & 63;
  const int wid = tid >> 6;
  const int len = lengths[b];

  __shared__ float4 Ks4[kS * 64];
  for (int i = tid; i < kS * 64; i += 256) Ks4[i] = ((const float4*)keys)[i];
  __syncthreads();

  const float4* X4 = (const float4*)inputs;
  for (int t = wid; t < len; t += 4) {
    float4 x = X4[((size_t)b * kT + t) * 64 + lane];
    float p[kS];
#pragma unroll
    for (int s = 0; s < kS; ++s) {
      float4 kk = Ks4[s * 64 + lane];
      p[s] = fmaf(x.x, kk.x, fmaf(x.y, kk.y, fmaf(x.z, kk.z, x.w * kk.w)));
    }
#pragma unroll
    for (int off = 32; off >= 1; off >>= 1) {
#pragma unroll
      for (int s = 0; s < kS; ++s) p[s] += __shfl_xor(p[s], off, 64);
    }
    if (lane == 0) {
      float* g = GK + ((size_t)b * kT + t) * kS;
#pragma unroll
      for (int s = 0; s < kS; ++s) g[s] = p[s];
    }
  }
}

// ---------------------------------------------------------------------------
// Kernel C: recurrence. One batch per 512-thread block (grid 512).
// __launch_bounds__(512, 1): 1 block/CU (CUDA blocks-per-CU semantics,
// confirmed by R3 counters: (512,2) capped VGPRs at 128 and spilled 1.1 GB)
// -> 2 waves/SIMD -> 256-VGPR cap -> persistent U slice fits, no spills.
// Thread (w=tid>>6, q=lane>>3, jj=lane&7) owns column quad 4*(w*8+jj) and
// k-range [q*32, q*32+32). U slice (32k x 4cols = 128 VGPR) loaded once.
// h computed IN-PLACE over the C accumulators (saves 32 VGPRs vs R3).
// ---------------------------------------------------------------------------
__global__ __launch_bounds__(512, 1)
void dynmem_rec2_kernel(const float* __restrict__ inputs,   // [B,T,D]
                        const int*   __restrict__ lengths,  // [B]
                        const float* __restrict__ keys,     // [S,D]
                        const float* __restrict__ U,        // [D,D]
                        const float* __restrict__ V,        // [D,D]
                        const float* __restrict__ gate_bias,
                        const float* __restrict__ state_bias,
                        const float* __restrict__ XW,       // [B,T,D]
                        const float* __restrict__ GK,       // [B,T,S]
                        float* __restrict__ out)            // [B,S,D]
{
  const int b = blockIdx.x;
  const int tid = threadIdx.x;
  const int w = tid >> 6;
  const int lane = tid & 63;
  const int q = lane >> 3;
  const int jj = lane & 7;
  const int quad = w * 8 + jj;
  const int kg = quad * 4;
  const int kgp = physk(kg);

  __shared__ float StL[kS * kStRow];
  __shared__ float KVL[kS * kD];
  __shared__ float redG[kS * 8];   // [s][wave]
  __shared__ float redN[kS * 8];   // [s][wave]

  // init state = keys (padded layout)
  for (int i = tid; i < kS * kD; i += 512) {
    int s = i >> 8, dd = i & 255;
    StL[s * kStRow + physk(dd)] = keys[i];
  }
  __syncthreads();

  // KV[s][d] = (keys @ V)[s][d] + state_bias[d]; thread (hh,d) does 4 s.
  {
    const int hh = tid >> 8, d = tid & 255;
    float a0 = 0.f, a1 = 0.f, a2 = 0.f, a3 = 0.f;
    const float* Vc = V + d;
    const float* Sb = StL + (hh * 4) * kStRow;
    for (int k = 0; k < kD; ++k) {
      float v = Vc[(size_t)k * kD];
      int pk = physk(k);
      a0 = fmaf(Sb[pk], v, a0);
      a1 = fmaf(Sb[kStRow + pk], v, a1);
      a2 = fmaf(Sb[2 * kStRow + pk], v, a2);
      a3 = fmaf(Sb[3 * kStRow + pk], v, a3);
    }
    float sb = state_bias[d];
    KVL[(hh * 4 + 0) * kD + d] = a0 + sb;
    KVL[(hh * 4 + 1) * kD + d] = a1 + sb;
    KVL[(hh * 4 + 2) * kD + d] = a2 + sb;
    KVL[(hh * 4 + 3) * kD + d] = a3 + sb;
  }

  // U slice -> registers (persistent, 128 VGPR)
  float4 u[32];
#pragma unroll
  for (int kk = 0; kk < 32; ++kk)
    u[kk] = *(const float4*)(U + (size_t)(q * 32 + kk) * kD + kg);

  const float gb = gate_bias[0];
  int len = lengths[b];
  len = len < 0 ? 0 : (len > kT ? kT : len);

  const float* Sq = StL + q * 36;  // q's k-chunk base (physical)
  __syncthreads();  // KV + St visible

  for (int t = 0; t < len; ++t) {
    const size_t rowoff = ((size_t)b * kT + t) * kD + kg;
    const float4 x4  = *(const float4*)(inputs + rowoff);
    const float4 xw4 = *(const float4*)(XW + rowoff);
    const float4 gk0 = *(const float4*)(GK + ((size_t)b * kT + t) * kS);
    const float4 gk1 = *(const float4*)(GK + ((size_t)b * kT + t) * kS + 4);
    const float gks[8] = {gk0.x, gk0.y, gk0.z, gk0.w, gk1.x, gk1.y, gk1.z, gk1.w};

    // ---- gate partials over own quad ----
    float pg[8];
#pragma unroll
    for (int s = 0; s < 8; ++s) {
      float4 sv = *(const float4*)(StL + s * kStRow + kgp);
      pg[s] = fmaf(x4.x, sv.x, fmaf(x4.y, sv.y, fmaf(x4.z, sv.z, x4.w * sv.w)));
    }
#pragma unroll
    for (int off = 1; off <= 4; off <<= 1) {
#pragma unroll
      for (int s = 0; s < 8; ++s) pg[s] += __shfl_xor(pg[s], off, 64);
    }
    if (lane == 0) {
#pragma unroll
      for (int s = 0; s < 8; ++s) redG[s * 8 + w] = pg[s];
    }

    // ---- matmul partials over own k-range (U in registers) ----
    float C[8][4];
#pragma unroll
    for (int s = 0; s < 8; ++s) {
      C[s][0] = 0.f; C[s][1] = 0.f; C[s][2] = 0.f; C[s][3] = 0.f;
    }
#pragma unroll
    for (int k4 = 0; k4 < 8; ++k4) {
#pragma unroll
      for (int s = 0; s < 8; ++s) {
        float4 sv = *(const float4*)(Sq + s * kStRow + 4 * k4);
        C[s][0] = fmaf(sv.x, u[4 * k4 + 0].x, C[s][0]);
        C[s][0] = fmaf(sv.y, u[4 * k4 + 1].x, C[s][0]);
        C[s][0] = fmaf(sv.z, u[4 * k4 + 2].x, C[s][0]);
        C[s][0] = fmaf(sv.w, u[4 * k4 + 3].x, C[s][0]);
        C[s][1] = fmaf(sv.x, u[4 * k4 + 0].y, C[s][1]);
        C[s][1] = fmaf(sv.y, u[4 * k4 + 1].y, C[s][1]);
        C[s][1] = fmaf(sv.z, u[4 * k4 + 2].y, C[s][1]);
        C[s][1] = fmaf(sv.w, u[4 * k4 + 3].y, C[s][1]);
        C[s][2] = fmaf(sv.x, u[4 * k4 + 0].z, C[s][2]);
        C[s][2] = fmaf(sv.y, u[4 * k4 + 1].z, C[s][2]);
        C[s][2] = fmaf(sv.z, u[4 * k4 + 2].z, C[s][2]);
        C[s][2] = fmaf(sv.w, u[4 * k4 + 3].z, C[s][2]);
        C[s][3] = fmaf(sv.x, u[4 * k4 + 0].w, C[s][3]);
        C[s][3] = fmaf(sv.y, u[4 * k4 + 1].w, C[s][3]);
        C[s][3] = fmaf(sv.z, u[4 * k4 + 2].w, C[s][3]);
        C[s][3] = fmaf(sv.w, u[4 * k4 + 3].w, C[s][3]);
      }
    }

    // k-split reduction across q (lane bits 3,4,5)
#pragma unroll
    for (int off = 8; off <= 32; off <<= 1) {
#pragma unroll
      for (int s = 0; s < 8; ++s) {
#pragma unroll
        for (int i = 0; i < 4; ++i) C[s][i] += __shfl_xor(C[s][i], off, 64);
      }
    }
    __syncthreads();  // B1: redG published; all St reads of the matmul done

    // ---- gates (redundant per thread; tiny) ----
    float g[8];
#pragma unroll
    for (int s = 0; s < 8; ++s) {
      float4 ra = *(const float4*)(redG + s * 8);
      float4 rb = *(const float4*)(redG + s * 8 + 4);
      float gs = (ra.x + ra.y) + (ra.z + ra.w) + (rb.x + rb.y) + (rb.z + rb.w);
      g[s] = 1.f / (1.f + expf(-(gs + gks[s] + gb)));
    }

    // ---- h = St + g*elu(C + KV + xW), IN-PLACE over C; norm partials ----
    float pn[8];
#pragma unroll
    for (int s = 0; s < 8; ++s) {
      float4 kv = *(const float4*)(KVL + s * kD + kg);
      float4 sv = *(const float4*)(StL + s * kStRow + kgp);
      float t0 = C[s][0] + kv.x + xw4.x; t0 = t0 > 0.f ? t0 : expm1f(t0);
      float t1 = C[s][1] + kv.y + xw4.y; t1 = t1 > 0.f ? t1 : expm1f(t1);
      float t2 = C[s][2] + kv.z + xw4.z; t2 = t2 > 0.f ? t2 : expm1f(t2);
      float t3 = C[s][3] + kv.w + xw4.w; t3 = t3 > 0.f ? t3 : expm1f(t3);
      C[s][0] = fmaf(g[s], t0, sv.x);
      C[s][1] = fmaf(g[s], t1, sv.y);
      C[s][2] = fmaf(g[s], t2, sv.z);
      C[s][3] = fmaf(g[s], t3, sv.w);
      pn[s] = C[s][0] * C[s][0] + C[s][1] * C[s][1] +
              C[s][2] * C[s][2] + C[s][3] * C[s][3];
    }
#pragma unroll
    for (int off = 1; off <= 4; off <<= 1) {
#pragma unroll
      for (int s = 0; s < 8; ++s) pn[s] += __shfl_xor(pn[s], off, 64);
    }
    if (lane == 0) {
#pragma unroll
      for (int s = 0; s < 8; ++s) redN[s * 8 + w] = pn[s];
    }
    __syncthreads();  // B2: redN published; St reads done before writes

    if (q == 0) {
#pragma unroll
      for (int s = 0; s < 8; ++s) {
        float4 ra = *(const float4*)(redN + s * 8);
        float4 rb = *(const float4*)(redN + s * 8 + 4);
        float nrm = sqrtf((ra.x + ra.y) + (ra.z + ra.w) +
                          (rb.x + rb.y) + (rb.z + rb.w));
        float inh = 1.f / fmaxf(nrm, 1e-12f);
        float4 sv = make_float4(C[0 + s][0] * inh, C[s][1] * inh,
                                C[s][2] * inh, C[s][3] * inh);
        *(float4*)(StL + s * kStRow + kgp) = sv;
      }
    }
    __syncthreads();  // B3: new state visible for next step
  }

  // final state -> out
  for (int i = tid; i < kS * kD; i += 512) {
    int s = i >> 8, dd = i & 255;
    out[(size_t)b * kS * kD + i] = StL[s * kStRow + physk(dd)];
  }
}

extern "C" void kernel_launch(void* const* d_in, const int* in_sizes, int n_in,
                              void* d_out, int out_size, void* d_ws, size_t ws_size,
                              hipStream_t stream) {
  const float* inputs     = (const float*)d_in[0];
  const int*   lengths    = (const int*)  d_in[1];
  const float* keys       = (const float*)d_in[2];
  const float* U          = (const float*)d_in[3];
  const float* V          = (const float*)d_in[4];
  const float* W          = (const float*)d_in[5];
  const float* gate_bias  = (const float*)d_in[6];
  const float* state_bias = (const float*)d_in[7];

  const size_t xw_elems = (size_t)kB * kT * kD;
  float* XW = (float*)d_ws;
  float* GK = (float*)d_ws + xw_elems;

  xw_gemm_kernel<<<dim3((kB * kT) / 32), dim3(256), 0, stream>>>(inputs, W, lengths, XW);
  gk_kernel<<<dim3(kB), dim3(256), 0, stream>>>(inputs, keys, lengths, GK);
  dynmem_rec2_kernel<<<dim3(kB), dim3(512), 0, stream>>>(
      inputs, lengths, keys, U, V, gate_bias, state_bias, XW, GK, (float*)d_out);
}

// Round 5
// 6440.801 us; speedup vs baseline: 1.0077x; 1.0077x over previous
//
#include <hip/hip_runtime.h>
#include <math.h>

namespace {
constexpr int kB = 512;
constexpr int kT = 256;
constexpr int kD = 256;
constexpr int kS = 8;
constexpr int kStRow = 288;  // padded LDS row stride: +4 floats per 32 (bank swizzle)

__device__ __forceinline__ int physk(int k) { return k + ((k >> 5) << 2); }
}

// ---------------------------------------------------------------------------
// Kernel A: XW[b,t,:] = inputs[b,t,:] @ W, skipping t >= lengths[b].
// ---------------------------------------------------------------------------
__global__ __launch_bounds__(256, 2)
void xw_gemm_kernel(const float* __restrict__ X, const float* __restrict__ W,
                    const int* __restrict__ lengths, float* __restrict__ XW) {
  const int m0 = blockIdx.x * 32;
  const int b = m0 >> 8;
  const int t0 = m0 & 255;
  if (t0 >= lengths[b]) return;

  __shared__ float Xs[32][kD];
  const int tid = threadIdx.x;
  const int j  = tid & 63;
  const int rg = tid >> 6;

  const float4* Xg4 = (const float4*)(X + (size_t)m0 * kD);
  float4* Xs4 = (float4*)&Xs[0][0];
  for (int i = tid; i < 32 * kD / 4; i += 256) Xs4[i] = Xg4[i];
  __syncthreads();

  float4 acc[8];
#pragma unroll
  for (int i = 0; i < 8; ++i) acc[i] = make_float4(0.f, 0.f, 0.f, 0.f);

  const float4* W4 = (const float4*)W;
  const float4* Xrow = (const float4*)&Xs[rg * 8][0];

  for (int k4 = 0; k4 < kD / 4; ++k4) {
    float4 w0 = W4[(size_t)(4 * k4 + 0) * 64 + j];
    float4 w1 = W4[(size_t)(4 * k4 + 1) * 64 + j];
    float4 w2 = W4[(size_t)(4 * k4 + 2) * 64 + j];
    float4 w3 = W4[(size_t)(4 * k4 + 3) * 64 + j];
#pragma unroll
    for (int i = 0; i < 8; ++i) {
      float4 x = Xrow[i * 64 + k4];
      acc[i].x = fmaf(x.x, w0.x, fmaf(x.y, w1.x, fmaf(x.z, w2.x, fmaf(x.w, w3.x, acc[i].x))));
      acc[i].y = fmaf(x.x, w0.y, fmaf(x.y, w1.y, fmaf(x.z, w2.y, fmaf(x.w, w3.y, acc[i].y))));
      acc[i].z = fmaf(x.x, w0.z, fmaf(x.y, w1.z, fmaf(x.z, w2.z, fmaf(x.w, w3.z, acc[i].z))));
      acc[i].w = fmaf(x.x, w0.w, fmaf(x.y, w1.w, fmaf(x.z, w2.w, fmaf(x.w, w3.w, acc[i].w))));
    }
  }
  float4* XW4 = (float4*)XW;
#pragma unroll
  for (int i = 0; i < 8; ++i)
    XW4[(size_t)(m0 + rg * 8 + i) * 64 + j] = acc[i];
}

// ---------------------------------------------------------------------------
// Kernel B: GK[b,t,s] = inputs[b,t,:] . keys[s,:], t < lengths[b] only.
// ---------------------------------------------------------------------------
__global__ __launch_bounds__(256, 4)
void gk_kernel(const float* __restrict__ inputs, const float* __restrict__ keys,
               const int* __restrict__ lengths, float* __restrict__ GK) {
  const int b = blockIdx.x;
  const int tid = threadIdx.x;
  const int lane = tid & 63;
  const int wid = tid >> 6;
  const int len = lengths[b];

  __shared__ float4 Ks4[kS * 64];
  for (int i = tid; i < kS * 64; i += 256) Ks4[i] = ((const float4*)keys)[i];
  __syncthreads();

  const float4* X4 = (const float4*)inputs;
  for (int t = wid; t < len; t += 4) {
    float4 x = X4[((size_t)b * kT + t) * 64 + lane];
    float p[kS];
#pragma unroll
    for (int s = 0; s < kS; ++s) {
      float4 kk = Ks4[s * 64 + lane];
      p[s] = fmaf(x.x, kk.x, fmaf(x.y, kk.y, fmaf(x.z, kk.z, x.w * kk.w)));
    }
#pragma unroll
    for (int off = 32; off >= 1; off >>= 1) {
#pragma unroll
      for (int s = 0; s < kS; ++s) p[s] += __shfl_xor(p[s], off, 64);
    }
    if (lane == 0) {
      float* g = GK + ((size_t)b * kT + t) * kS;
#pragma unroll
      for (int s = 0; s < kS; ++s) g[s] = p[s];
    }
  }
}

// ---------------------------------------------------------------------------
// Kernel C: recurrence. One batch per 512-thread block (grid 512).
// R3/R4 lesson: __launch_bounds__(512,{1,2}) left LLVM's default occupancy
// floor (4 waves/EU -> 128-VGPR budget) in place; the ~200-VGPR working set
// (persistent U slice = 128 regs) spilled to scratch -> 1.1 GB/dispatch HBM
// writes. Fix: explicit backend attrs amdgpu_waves_per_eu(1,2) -> 256-VGPR
// budget -> no spills.
// Thread (w=tid>>6, q=lane>>3, jj=lane&7) owns column quad 4*(w*8+jj) and
// k-range [q*32, q*32+32). U slice (32k x 4cols = 128 VGPR) loaded once.
// ---------------------------------------------------------------------------
__global__ __attribute__((amdgpu_flat_work_group_size(512, 512),
                          amdgpu_waves_per_eu(1, 2)))
void dynmem_rec2_kernel(const float* __restrict__ inputs,   // [B,T,D]
                        const int*   __restrict__ lengths,  // [B]
                        const float* __restrict__ keys,     // [S,D]
                        const float* __restrict__ U,        // [D,D]
                        const float* __restrict__ V,        // [D,D]
                        const float* __restrict__ gate_bias,
                        const float* __restrict__ state_bias,
                        const float* __restrict__ XW,       // [B,T,D]
                        const float* __restrict__ GK,       // [B,T,S]
                        float* __restrict__ out)            // [B,S,D]
{
  const int b = blockIdx.x;
  const int tid = threadIdx.x;
  const int w = tid >> 6;
  const int lane = tid & 63;
  const int q = lane >> 3;
  const int jj = lane & 7;
  const int quad = w * 8 + jj;
  const int kg = quad * 4;
  const int kgp = physk(kg);

  __shared__ float StL[kS * kStRow];
  __shared__ float KVL[kS * kD];
  __shared__ float redG[kS * 8];   // [s][wave]
  __shared__ float redN[kS * 8];   // [s][wave]

  // init state = keys (padded layout)
  for (int i = tid; i < kS * kD; i += 512) {
    int s = i >> 8, dd = i & 255;
    StL[s * kStRow + physk(dd)] = keys[i];
  }
  __syncthreads();

  // KV[s][d] = (keys @ V)[s][d] + state_bias[d]; thread (hh,d) does 4 s.
  {
    const int hh = tid >> 8, d = tid & 255;
    float a0 = 0.f, a1 = 0.f, a2 = 0.f, a3 = 0.f;
    const float* Vc = V + d;
    const float* Sb = StL + (hh * 4) * kStRow;
    for (int k = 0; k < kD; ++k) {
      float v = Vc[(size_t)k * kD];
      int pk = physk(k);
      a0 = fmaf(Sb[pk], v, a0);
      a1 = fmaf(Sb[kStRow + pk], v, a1);
      a2 = fmaf(Sb[2 * kStRow + pk], v, a2);
      a3 = fmaf(Sb[3 * kStRow + pk], v, a3);
    }
    float sb = state_bias[d];
    KVL[(hh * 4 + 0) * kD + d] = a0 + sb;
    KVL[(hh * 4 + 1) * kD + d] = a1 + sb;
    KVL[(hh * 4 + 2) * kD + d] = a2 + sb;
    KVL[(hh * 4 + 3) * kD + d] = a3 + sb;
  }

  // U slice -> registers (persistent, 128 VGPR)
  float4 u[32];
#pragma unroll
  for (int kk = 0; kk < 32; ++kk)
    u[kk] = *(const float4*)(U + (size_t)(q * 32 + kk) * kD + kg);

  const float gb = gate_bias[0];
  int len = lengths[b];
  len = len < 0 ? 0 : (len > kT ? kT : len);

  const float* Sq = StL + q * 36;  // q's k-chunk base (physical)
  __syncthreads();  // KV + St visible

  for (int t = 0; t < len; ++t) {
    const size_t rowoff = ((size_t)b * kT + t) * kD + kg;
    const float4 x4  = *(const float4*)(inputs + rowoff);
    const float4 xw4 = *(const float4*)(XW + rowoff);
    const float4 gk0 = *(const float4*)(GK + ((size_t)b * kT + t) * kS);
    const float4 gk1 = *(const float4*)(GK + ((size_t)b * kT + t) * kS + 4);
    const float gks[8] = {gk0.x, gk0.y, gk0.z, gk0.w, gk1.x, gk1.y, gk1.z, gk1.w};

    // ---- gate partials over own quad ----
    float pg[8];
#pragma unroll
    for (int s = 0; s < 8; ++s) {
      float4 sv = *(const float4*)(StL + s * kStRow + kgp);
      pg[s] = fmaf(x4.x, sv.x, fmaf(x4.y, sv.y, fmaf(x4.z, sv.z, x4.w * sv.w)));
    }
#pragma unroll
    for (int off = 1; off <= 4; off <<= 1) {
#pragma unroll
      for (int s = 0; s < 8; ++s) pg[s] += __shfl_xor(pg[s], off, 64);
    }
    if (lane == 0) {
#pragma unroll
      for (int s = 0; s < 8; ++s) redG[s * 8 + w] = pg[s];
    }

    // ---- matmul partials over own k-range (U in registers) ----
    float C[8][4];
#pragma unroll
    for (int s = 0; s < 8; ++s) {
      C[s][0] = 0.f; C[s][1] = 0.f; C[s][2] = 0.f; C[s][3] = 0.f;
    }
#pragma unroll
    for (int k4 = 0; k4 < 8; ++k4) {
#pragma unroll
      for (int s = 0; s < 8; ++s) {
        float4 sv = *(const float4*)(Sq + s * kStRow + 4 * k4);
        C[s][0] = fmaf(sv.x, u[4 * k4 + 0].x, C[s][0]);
        C[s][0] = fmaf(sv.y, u[4 * k4 + 1].x, C[s][0]);
        C[s][0] = fmaf(sv.z, u[4 * k4 + 2].x, C[s][0]);
        C[s][0] = fmaf(sv.w, u[4 * k4 + 3].x, C[s][0]);
        C[s][1] = fmaf(sv.x, u[4 * k4 + 0].y, C[s][1]);
        C[s][1] = fmaf(sv.y, u[4 * k4 + 1].y, C[s][1]);
        C[s][1] = fmaf(sv.z, u[4 * k4 + 2].y, C[s][1]);
        C[s][1] = fmaf(sv.w, u[4 * k4 + 3].y, C[s][1]);
        C[s][2] = fmaf(sv.x, u[4 * k4 + 0].z, C[s][2]);
        C[s][2] = fmaf(sv.y, u[4 * k4 + 1].z, C[s][2]);
        C[s][2] = fmaf(sv.z, u[4 * k4 + 2].z, C[s][2]);
        C[s][2] = fmaf(sv.w, u[4 * k4 + 3].z, C[s][2]);
        C[s][3] = fmaf(sv.x, u[4 * k4 + 0].w, C[s][3]);
        C[s][3] = fmaf(sv.y, u[4 * k4 + 1].w, C[s][3]);
        C[s][3] = fmaf(sv.z, u[4 * k4 + 2].w, C[s][3]);
        C[s][3] = fmaf(sv.w, u[4 * k4 + 3].w, C[s][3]);
      }
    }

    // k-split reduction across q (lane bits 3,4,5)
#pragma unroll
    for (int off = 8; off <= 32; off <<= 1) {
#pragma unroll
      for (int s = 0; s < 8; ++s) {
#pragma unroll
        for (int i = 0; i < 4; ++i) C[s][i] += __shfl_xor(C[s][i], off, 64);
      }
    }
    __syncthreads();  // B1: redG published; all St reads of the matmul done

    // ---- gates (redundant per thread; tiny) ----
    float g[8];
#pragma unroll
    for (int s = 0; s < 8; ++s) {
      float4 ra = *(const float4*)(redG + s * 8);
      float4 rb = *(const float4*)(redG + s * 8 + 4);
      float gs = (ra.x + ra.y) + (ra.z + ra.w) + (rb.x + rb.y) + (rb.z + rb.w);
      g[s] = 1.f / (1.f + expf(-(gs + gks[s] + gb)));
    }

    // ---- h = St + g*elu(C + KV + xW), IN-PLACE over C; norm partials ----
    float pn[8];
#pragma unroll
    for (int s = 0; s < 8; ++s) {
      float4 kv = *(const float4*)(KVL + s * kD + kg);
      float4 sv = *(const float4*)(StL + s * kStRow + kgp);
      float t0 = C[s][0] + kv.x + xw4.x; t0 = t0 > 0.f ? t0 : expm1f(t0);
      float t1 = C[s][1] + kv.y + xw4.y; t1 = t1 > 0.f ? t1 : expm1f(t1);
      float t2 = C[s][2] + kv.z + xw4.z; t2 = t2 > 0.f ? t2 : expm1f(t2);
      float t3 = C[s][3] + kv.w + xw4.w; t3 = t3 > 0.f ? t3 : expm1f(t3);
      C[s][0] = fmaf(g[s], t0, sv.x);
      C[s][1] = fmaf(g[s], t1, sv.y);
      C[s][2] = fmaf(g[s], t2, sv.z);
      C[s][3] = fmaf(g[s], t3, sv.w);
      pn[s] = C[s][0] * C[s][0] + C[s][1] * C[s][1] +
              C[s][2] * C[s][2] + C[s][3] * C[s][3];
    }
#pragma unroll
    for (int off = 1; off <= 4; off <<= 1) {
#pragma unroll
      for (int s = 0; s < 8; ++s) pn[s] += __shfl_xor(pn[s], off, 64);
    }
    if (lane == 0) {
#pragma unroll
      for (int s = 0; s < 8; ++s) redN[s * 8 + w] = pn[s];
    }
    __syncthreads();  // B2: redN published; St reads done before writes

    if (q == 0) {
#pragma unroll
      for (int s = 0; s < 8; ++s) {
        float4 ra = *(const float4*)(redN + s * 8);
        float4 rb = *(const float4*)(redN + s * 8 + 4);
        float nrm = sqrtf((ra.x + ra.y) + (ra.z + ra.w) +
                          (rb.x + rb.y) + (rb.z + rb.w));
        float inh = 1.f / fmaxf(nrm, 1e-12f);
        float4 sv = make_float4(C[s][0] * inh, C[s][1] * inh,
                                C[s][2] * inh, C[s][3] * inh);
        *(float4*)(StL + s * kStRow + kgp) = sv;
      }
    }
    __syncthreads();  // B3: new state visible for next step
  }

  // final state -> out
  for (int i = tid; i < kS * kD; i += 512) {
    int s = i >> 8, dd = i & 255;
    out[(size_t)b * kS * kD + i] = StL[s * kStRow + physk(dd)];
  }
}

extern "C" void kernel_launch(void* const* d_in, const int* in_sizes, int n_in,
                              void* d_out, int out_size, void* d_ws, size_t ws_size,
                              hipStream_t stream) {
  const float* inputs     = (const float*)d_in[0];
  const int*   lengths    = (const int*)  d_in[1];
  const float* keys       = (const float*)d_in[2];
  const float* U          = (const float*)d_in[3];
  const float* V          = (const float*)d_in[4];
  const float* W          = (const float*)d_in[5];
  const float* gate_bias  = (const float*)d_in[6];
  const float* state_bias = (const float*)d_in[7];

  const size_t xw_elems = (size_t)kB * kT * kD;
  float* XW = (float*)d_ws;
  float* GK = (float*)d_ws + xw_elems;

  xw_gemm_kernel<<<dim3((kB * kT) / 32), dim3(256), 0, stream>>>(inputs, W, lengths, XW);
  gk_kernel<<<dim3(kB), dim3(256), 0, stream>>>(inputs, keys, lengths, GK);
  dynmem_rec2_kernel<<<dim3(kB), dim3(512), 0, stream>>>(
      inputs, lengths, keys, U, V, gate_bias, state_bias, XW, GK, (float*)d_out);
}

// Round 6
// 3432.270 us; speedup vs baseline: 1.8910x; 1.8765x over previous
//
#include <hip/hip_runtime.h>
#include <math.h>

namespace {
constexpr int kB = 512;
constexpr int kT = 256;
constexpr int kD = 256;
constexpr int kS = 8;
constexpr int kStRow = 292;  // 288 data (physk layout) + 4; 292 % 32 == 4
constexpr int kRedRow = 20;  // reduction table row stride; 20q mod 32 distinct

__device__ __forceinline__ int physk(int k) { return k + ((k >> 5) << 2); }
}

// ---------------------------------------------------------------------------
// Kernel A: XW[b,t,:] = inputs[b,t,:] @ W, skipping t >= lengths[b].
// ---------------------------------------------------------------------------
__global__ __launch_bounds__(256, 2)
void xw_gemm_kernel(const float* __restrict__ X, const float* __restrict__ W,
                    const int* __restrict__ lengths, float* __restrict__ XW) {
  const int m0 = blockIdx.x * 32;
  const int b = m0 >> 8;
  const int t0 = m0 & 255;
  if (t0 >= lengths[b]) return;

  __shared__ float Xs[32][kD];
  const int tid = threadIdx.x;
  const int j  = tid & 63;
  const int rg = tid >> 6;

  const float4* Xg4 = (const float4*)(X + (size_t)m0 * kD);
  float4* Xs4 = (float4*)&Xs[0][0];
  for (int i = tid; i < 32 * kD / 4; i += 256) Xs4[i] = Xg4[i];
  __syncthreads();

  float4 acc[8];
#pragma unroll
  for (int i = 0; i < 8; ++i) acc[i] = make_float4(0.f, 0.f, 0.f, 0.f);

  const float4* W4 = (const float4*)W;
  const float4* Xrow = (const float4*)&Xs[rg * 8][0];

  for (int k4 = 0; k4 < kD / 4; ++k4) {
    float4 w0 = W4[(size_t)(4 * k4 + 0) * 64 + j];
    float4 w1 = W4[(size_t)(4 * k4 + 1) * 64 + j];
    float4 w2 = W4[(size_t)(4 * k4 + 2) * 64 + j];
    float4 w3 = W4[(size_t)(4 * k4 + 3) * 64 + j];
#pragma unroll
    for (int i = 0; i < 8; ++i) {
      float4 x = Xrow[i * 64 + k4];
      acc[i].x = fmaf(x.x, w0.x, fmaf(x.y, w1.x, fmaf(x.z, w2.x, fmaf(x.w, w3.x, acc[i].x))));
      acc[i].y = fmaf(x.x, w0.y, fmaf(x.y, w1.y, fmaf(x.z, w2.y, fmaf(x.w, w3.y, acc[i].y))));
      acc[i].z = fmaf(x.x, w0.z, fmaf(x.y, w1.z, fmaf(x.z, w2.z, fmaf(x.w, w3.z, acc[i].z))));
      acc[i].w = fmaf(x.x, w0.w, fmaf(x.y, w1.w, fmaf(x.z, w2.w, fmaf(x.w, w3.w, acc[i].w))));
    }
  }
  float4* XW4 = (float4*)XW;
#pragma unroll
  for (int i = 0; i < 8; ++i)
    XW4[(size_t)(m0 + rg * 8 + i) * 64 + j] = acc[i];
}

// ---------------------------------------------------------------------------
// Kernel B: GK[b,t,s] = inputs[b,t,:] . keys[s,:], t < lengths[b] only.
// ---------------------------------------------------------------------------
__global__ __launch_bounds__(256, 4)
void gk_kernel(const float* __restrict__ inputs, const float* __restrict__ keys,
               const int* __restrict__ lengths, float* __restrict__ GK) {
  const int b = blockIdx.x;
  const int tid = threadIdx.x;
  const int lane = tid & 63;
  const int wid = tid >> 6;
  const int len = lengths[b];

  __shared__ float4 Ks4[kS * 64];
  for (int i = tid; i < kS * 64; i += 256) Ks4[i] = ((const float4*)keys)[i];
  __syncthreads();

  const float4* X4 = (const float4*)inputs;
  for (int t = wid; t < len; t += 4) {
    float4 x = X4[((size_t)b * kT + t) * 64 + lane];
    float p[kS];
#pragma unroll
    for (int s = 0; s < kS; ++s) {
      float4 kk = Ks4[s * 64 + lane];
      p[s] = fmaf(x.x, kk.x, fmaf(x.y, kk.y, fmaf(x.z, kk.z, x.w * kk.w)));
    }
#pragma unroll
    for (int off = 32; off >= 1; off >>= 1) {
#pragma unroll
      for (int s = 0; s < kS; ++s) p[s] += __shfl_xor(p[s], off, 64);
    }
    if (lane == 0) {
      float* g = GK + ((size_t)b * kT + t) * kS;
#pragma unroll
      for (int s = 0; s < kS; ++s) g[s] = p[s];
    }
  }
}

// ---------------------------------------------------------------------------
// Kernel C: recurrence. ONE batch per 1024-thread block (grid 512).
// R3-R5 lesson: the backend's 128-VGPR budget is immovable (launch_bounds and
// amdgpu_waves_per_eu both ignored); a >128-reg working set spills ~32B/thr/step
// (1.1 GB/dispatch). This version fits in 128: per-thread U slice is
// 2 cols x 32 k = 32 float2 = 64 VGPR.
// Thread (w=tid>>6, jj=lane>>3, q=lane&7): col-pair p=w*8+jj (cols 2p,2p+1),
// k-chunk [q*32, q*32+32). k-reduction: shfl_xor 1,2,4. Column reductions
// (gate/norm): shfl_xor 8,16,32 + [8][20] LDS tables. Gate finalize, h-update
// and normalize are s-split by q (lane handles s=q only) -> tiny epilogue.
// ---------------------------------------------------------------------------
__global__ __launch_bounds__(1024)
void dynmem_rec3_kernel(const float* __restrict__ inputs,   // [B,T,D]
                        const int*   __restrict__ lengths,  // [B]
                        const float* __restrict__ keys,     // [S,D]
                        const float* __restrict__ U,        // [D,D]
                        const float* __restrict__ V,        // [D,D]
                        const float* __restrict__ gate_bias,
                        const float* __restrict__ state_bias,
                        const float* __restrict__ XW,       // [B,T,D]
                        const float* __restrict__ GK,       // [B,T,S]
                        float* __restrict__ out)            // [B,S,D]
{
  const int b = blockIdx.x;
  const int tid = threadIdx.x;
  const int w = tid >> 6;        // 0..15
  const int lane = tid & 63;
  const int q = lane & 7;        // k-chunk AND the state s this lane finalizes
  const int jj = lane >> 3;      // 0..7
  const int p = w * 8 + jj;      // col-pair index, 0..127
  const int c0 = 2 * p;
  const int c0p = physk(c0);     // both cols in same 32-group (c0 even)

  __shared__ float StL[kS * kStRow];
  __shared__ float KVL[kS * kD];
  __shared__ float redG[kS * kRedRow];
  __shared__ float redN[kS * kRedRow];

  // init state = keys (padded layout)
  for (int i = tid; i < kS * kD; i += 1024) {
    int s = i >> 8, dd = i & 255;
    StL[s * kStRow + physk(dd)] = keys[i];
  }
  __syncthreads();

  // KV[s][d] = (keys @ V)[s][d] + state_bias[d]; thread (hh,d) does 2 s.
  {
    const int hh = tid >> 8, d = tid & 255;   // hh in [0,4)
    float a0 = 0.f, a1 = 0.f;
    const float* Vc = V + d;
    const float* S0 = StL + (2 * hh) * kStRow;
    const float* S1 = StL + (2 * hh + 1) * kStRow;
    for (int k = 0; k < kD; ++k) {
      float v = Vc[(size_t)k * kD];
      int pk = physk(k);
      a0 = fmaf(S0[pk], v, a0);
      a1 = fmaf(S1[pk], v, a1);
    }
    float sb = state_bias[d];
    KVL[(2 * hh) * kD + d] = a0 + sb;
    KVL[(2 * hh + 1) * kD + d] = a1 + sb;
  }

  // persistent U slice: rows q*32..q*32+31, cols c0..c0+1  (64 VGPRs)
  float2 u2[32];
#pragma unroll
  for (int kk = 0; kk < 32; ++kk)
    u2[kk] = *(const float2*)(U + (size_t)(q * 32 + kk) * kD + c0);

  const float gb = gate_bias[0];
  int len = lengths[b];
  len = len < 0 ? 0 : (len > kT ? kT : len);

  __syncthreads();  // KVL + StL ready

  // loop-invariant: KV for row q at this lane's cols; own state cols in regs
  const float2 kvq = *(const float2*)(KVL + q * kD + c0);
  float2 sreg = *(const float2*)(StL + q * kStRow + c0p);

  const float* Sq = StL + q * 36;  // physical base of k-chunk q within a row

  for (int t = 0; t < len; ++t) {
    const size_t base = (size_t)b * kT + t;
    const float2 x2  = *(const float2*)(inputs + base * kD + c0);
    const float2 xw2 = *(const float2*)(XW + base * kD + c0);
    const float4 gka = *(const float4*)(GK + base * kS);
    const float4 gkb = *(const float4*)(GK + base * kS + 4);
    float gkq = gka.x;
    gkq = (q == 1) ? gka.y : gkq;
    gkq = (q == 2) ? gka.z : gkq;
    gkq = (q == 3) ? gka.w : gkq;
    gkq = (q == 4) ? gkb.x : gkq;
    gkq = (q == 5) ? gkb.y : gkq;
    gkq = (q == 6) ? gkb.z : gkq;
    gkq = (q == 7) ? gkb.w : gkq;

    // ---- gate partial for s=q over own col pair (sreg == St[q][c0..c0+1]) ----
    float pg = fmaf(x2.x, sreg.x, x2.y * sreg.y);
    pg += __shfl_xor(pg, 8, 64);
    pg += __shfl_xor(pg, 16, 64);
    pg += __shfl_xor(pg, 32, 64);
    if (lane < 8) redG[lane * kRedRow + w] = pg;  // lane == q here

    // ---- matmul partials: C[s] over k-chunk q, 2 cols (U in registers) ----
    float C0[8], C1[8];
#pragma unroll
    for (int s = 0; s < 8; ++s) { C0[s] = 0.f; C1[s] = 0.f; }
#pragma unroll
    for (int k4 = 0; k4 < 8; ++k4) {
#pragma unroll
      for (int s = 0; s < 8; ++s) {
        float4 sv = *(const float4*)(Sq + s * kStRow + 4 * k4);
        C0[s] = fmaf(sv.x, u2[4 * k4 + 0].x, C0[s]);
        C0[s] = fmaf(sv.y, u2[4 * k4 + 1].x, C0[s]);
        C0[s] = fmaf(sv.z, u2[4 * k4 + 2].x, C0[s]);
        C0[s] = fmaf(sv.w, u2[4 * k4 + 3].x, C0[s]);
        C1[s] = fmaf(sv.x, u2[4 * k4 + 0].y, C1[s]);
        C1[s] = fmaf(sv.y, u2[4 * k4 + 1].y, C1[s]);
        C1[s] = fmaf(sv.z, u2[4 * k4 + 2].y, C1[s]);
        C1[s] = fmaf(sv.w, u2[4 * k4 + 3].y, C1[s]);
      }
    }
    // k-split reduction across q (lane bits 0,1,2)
#pragma unroll
    for (int off = 1; off <= 4; off <<= 1) {
#pragma unroll
      for (int s = 0; s < 8; ++s) {
        C0[s] += __shfl_xor(C0[s], off, 64);
        C1[s] += __shfl_xor(C1[s], off, 64);
      }
    }
    __syncthreads();  // B1: redG complete; all StL matmul reads done

    // ---- finalize gate for s=q ----
    float4 ra = *(const float4*)(redG + q * kRedRow);
    float4 rb = *(const float4*)(redG + q * kRedRow + 4);
    float4 rc = *(const float4*)(redG + q * kRedRow + 8);
    float4 rd = *(const float4*)(redG + q * kRedRow + 12);
    float gs = ((ra.x + ra.y) + (ra.z + ra.w)) + ((rb.x + rb.y) + (rb.z + rb.w)) +
               ((rc.x + rc.y) + (rc.z + rc.w)) + ((rd.x + rd.y) + (rd.z + rd.w)) +
               gkq + gb;
    float gq = 1.f / (1.f + expf(-gs));

    // select this lane's s=q matmul outputs (cndmask chain, no dynamic index)
    float ca = C0[0], cb = C1[0];
#pragma unroll
    for (int s = 1; s < 8; ++s) {
      if (q == s) { ca = C0[s]; cb = C1[s]; }
    }

    // ---- h for row s=q, own 2 cols ----
    float t0 = ca + kvq.x + xw2.x; t0 = t0 > 0.f ? t0 : expm1f(t0);
    float t1 = cb + kvq.y + xw2.y; t1 = t1 > 0.f ? t1 : expm1f(t1);
    float h0 = fmaf(gq, t0, sreg.x);
    float h1 = fmaf(gq, t1, sreg.y);
    float pn = fmaf(h0, h0, h1 * h1);
    pn += __shfl_xor(pn, 8, 64);
    pn += __shfl_xor(pn, 16, 64);
    pn += __shfl_xor(pn, 32, 64);
    if (jj == 0) redN[q * kRedRow + w] = pn;  // lane == q
    __syncthreads();  // B2: redN complete

    // ---- normalize row s=q, write own 2 cols ----
    float4 na = *(const float4*)(redN + q * kRedRow);
    float4 nb = *(const float4*)(redN + q * kRedRow + 4);
    float4 nc = *(const float4*)(redN + q * kRedRow + 8);
    float4 nd = *(const float4*)(redN + q * kRedRow + 12);
    float nsum = ((na.x + na.y) + (na.z + na.w)) + ((nb.x + nb.y) + (nb.z + nb.w)) +
                 ((nc.x + nc.y) + (nc.z + nc.w)) + ((nd.x + nd.y) + (nd.z + nd.w));
    float inh = 1.f / fmaxf(sqrtf(nsum), 1e-12f);
    sreg.x = h0 * inh;
    sreg.y = h1 * inh;
    *(float2*)(StL + q * kStRow + c0p) = sreg;
    __syncthreads();  // B3: new state visible for next step
  }

  // final state -> out
  for (int i = tid; i < kS * kD; i += 1024) {
    int s = i >> 8, dd = i & 255;
    out[(size_t)b * kS * kD + i] = StL[s * kStRow + physk(dd)];
  }
}

extern "C" void kernel_launch(void* const* d_in, const int* in_sizes, int n_in,
                              void* d_out, int out_size, void* d_ws, size_t ws_size,
                              hipStream_t stream) {
  const float* inputs     = (const float*)d_in[0];
  const int*   lengths    = (const int*)  d_in[1];
  const float* keys       = (const float*)d_in[2];
  const float* U          = (const float*)d_in[3];
  const float* V          = (const float*)d_in[4];
  const float* W          = (const float*)d_in[5];
  const float* gate_bias  = (const float*)d_in[6];
  const float* state_bias = (const float*)d_in[7];

  const size_t xw_elems = (size_t)kB * kT * kD;
  float* XW = (float*)d_ws;
  float* GK = (float*)d_ws + xw_elems;

  xw_gemm_kernel<<<dim3((kB * kT) / 32), dim3(256), 0, stream>>>(inputs, W, lengths, XW);
  gk_kernel<<<dim3(kB), dim3(256), 0, stream>>>(inputs, keys, lengths, GK);
  dynmem_rec3_kernel<<<dim3(kB), dim3(1024), 0, stream>>>(
      inputs, lengths, keys, U, V, gate_bias, state_bias, XW, GK, (float*)d_out);
}